// Round 14
// baseline (160.154 us; speedup 1.0000x reference)
//
#include <hip/hip_runtime.h>
#include <stdint.h>

typedef float v4f  __attribute__((ext_vector_type(4)));
typedef float v16f __attribute__((ext_vector_type(16)));
typedef short v8s  __attribute__((ext_vector_type(8)));
typedef uint32_t u32;

#define DEVI static __device__ __forceinline__

// fp32 -> bf16 (RNE), raw bits
DEVI unsigned short f2bf(float f) {
    u32 u = __builtin_bit_cast(u32, f);
    u = (u + 0x7fffu + ((u >> 16) & 1u)) >> 16;
    return (unsigned short)u;
}
DEVI float bf2f(unsigned short h) {
    u32 u = ((u32)h) << 16;
    return __builtin_bit_cast(float, u);
}

// raw v_exp_f32: OCML exp2f without -ffast-math wraps the instruction in a
// ~5-op guarded range-fixup; our exponents are in-range. (round-12: -15us)
DEVI float fexp2(float x) {
#if __has_builtin(__builtin_amdgcn_exp2f)
    return __builtin_amdgcn_exp2f(x);
#else
    float r;
    asm("v_exp_f32 %0, %1" : "=v"(r) : "v"(x));
    return r;
#endif
}

// async global->LDS, 16B per lane. HW dest = wave-uniform base + lane*16.
template <typename T>
DEVI void async16(const T* g, T* l) {
    __builtin_amdgcn_global_load_lds(
        (const __attribute__((address_space(1))) u32*)g,
        (__attribute__((address_space(3))) u32*)l, 16, 0, 0);
}

DEVI v4f bmfma(v8s a, v8s b, v4f c) {
    return __builtin_amdgcn_mfma_f32_16x16x32_bf16(a, b, c, 0, 0, 0);
}
DEVI v16f bmfma32(v8s a, v8s b, v16f c) {
    return __builtin_amdgcn_mfma_f32_32x32x16_bf16(a, b, c, 0, 0, 0);
}

#if __has_builtin(__builtin_amdgcn_permlane32_swap)
#define HAVE_PLSWAP 1
typedef unsigned int v2u __attribute__((ext_vector_type(2)));
#endif

// lo = [a.lanes0-31 | b.lanes0-31], hi = [a.lanes32-63 | b.lanes32-63]
DEVI void swap32(u32 a, u32 b, u32& lo, u32& hi) {
#ifdef HAVE_PLSWAP
    v2u r = __builtin_amdgcn_permlane32_swap(a, b, false, false);
    lo = r.x; hi = r.y;
#else
    u32 ax = __shfl_xor(a, 32), bx = __shfl_xor(b, 32);
    int hh = (threadIdx.x & 63) >> 5;
    lo = hh ? bx : a;
    hi = hh ? b : ax;
#endif
}

static const size_t HSZ = 32ull * 2048 * 64;  // per q/k/v region, elements

// ---------------------------------------------------------------------------
// prep_all: one launch for the 3 input-prep passes.
// fp32 [R][512] -> bf16, row sum-of-squares, optional row sum.
__launch_bounds__(256, 2)
__global__ void prep_all(const float* __restrict__ X, const float* __restrict__ WQ,
                         const float* __restrict__ WO,
                         unsigned short* __restrict__ Xb, unsigned short* __restrict__ WQb,
                         unsigned short* __restrict__ WOb,
                         float* __restrict__ xsq, float* __restrict__ wqsq,
                         float* __restrict__ wosq, float* __restrict__ wors)
{
    const int bid = blockIdx.x;
    const int w = threadIdx.x >> 6, lane = threadIdx.x & 63;
    const float* src; unsigned short* dst; float* Sq; float* Rs = nullptr;
    int r;
    if (bid < 2048)      { src = X;  dst = Xb;  Sq = xsq;  r = bid * 4 + w; }
    else if (bid < 2432) { src = WQ; dst = WQb; Sq = wqsq; r = (bid - 2048) * 4 + w; }
    else                 { src = WO; dst = WOb; Sq = wosq; Rs = wors; r = (bid - 2432) * 4 + w; }

    const float* xr = src + (size_t)r * 512 + lane * 8;
    float4 a = *(const float4*)xr;
    float4 c = *(const float4*)(xr + 4);
    float s = a.x*a.x + a.y*a.y + a.z*a.z + a.w*a.w
            + c.x*c.x + c.y*c.y + c.z*c.z + c.w*c.w;
    float sm = a.x + a.y + a.z + a.w + c.x + c.y + c.z + c.w;
    uint4 pkv;
    unsigned short* e = (unsigned short*)&pkv;
    e[0] = f2bf(a.x); e[1] = f2bf(a.y); e[2] = f2bf(a.z); e[3] = f2bf(a.w);
    e[4] = f2bf(c.x); e[5] = f2bf(c.y); e[6] = f2bf(c.z); e[7] = f2bf(c.w);
    *(uint4*)(dst + (size_t)r * 512 + lane * 8) = pkv;
#pragma unroll
    for (int d = 32; d > 0; d >>= 1) {
        s  += __shfl_xor(s, d);
        sm += __shfl_xor(sm, d);
    }
    if (lane == 0) { Sq[r] = s; if (Rs) Rs[r] = sm; }
}

// ---------------------------------------------------------------------------
// QKV cdist GEMM v3 (round-13, kept): 128x128 tile, BK=32, 4-buffer depth-2
// prefetch, ONE barrier per K-step, counted vmcnt.
//   tt=0 (q): *2*scale*log2e -> q'' region [bh][i][d]
//   tt=1 (k): -> k' region [bh][j][d]; fused ksqc[bh][j] = -sum_d k'^2 * CK
//   tt=2 (v): -> v' region TRANSPOSED [bh][d][j], via LDS-transpose epilogue
__launch_bounds__(256, 2)
__global__ void gemm_cdist(const unsigned short* __restrict__ A,
                           const unsigned short* __restrict__ B,
                           const float* __restrict__ Asq,
                           const float* __restrict__ Bsq,
                           unsigned short* __restrict__ QKV,
                           float* __restrict__ Ksqc)
{
    // [buf 0..3][A 4096 | B 4096] shorts = 64 KB. Reused as lT in epilogue.
    __shared__ unsigned short lsm[4 * 8192];
    const int t = threadIdx.x;
    const int lane = t & 63, w = t >> 6;
    const int low = lane & 15, quad = lane >> 4;
    const int wm = w & 1, wn = w >> 1;
    const int tM = blockIdx.x * 128, tN = blockIdx.y * 128;

    v4f acc[4][4];
#pragma unroll
    for (int a = 0; a < 4; ++a)
#pragma unroll
        for (int b = 0; b < 4; ++b) acc[a][b] = (v4f){0.f, 0.f, 0.f, 0.f};

    int kstage = 0;
    auto STAGE = [&](int buf) {   // 4 async16 per thread (2 A + 2 B), uniform
        unsigned short* lA = lsm + buf * 8192;
        unsigned short* lB = lA + 4096;
#pragma unroll
        for (int is = 0; is < 2; ++is) {
            int slot = is * 256 + t;                 // 0..511
            int r = slot >> 2, bp = slot & 3, bs = bp ^ (r & 3);
            async16(A + (size_t)(tM + r) * 512 + kstage + bs * 8, lA + slot * 8);
            async16(B + (size_t)(tN + r) * 512 + kstage + bs * 8, lB + slot * 8);
        }
        kstage += 32;
    };

    STAGE(0);
    STAGE(1);   // depth-2 prologue; no drain (iter-0 wait handles it)

#pragma unroll
    for (int iter = 0; iter < 16; ++iter) {
        if (iter <= 13) STAGE((iter + 2) & 3);
        if (iter <= 13)      asm volatile("s_waitcnt vmcnt(8)" ::: "memory");
        else if (iter == 14) asm volatile("s_waitcnt vmcnt(4)" ::: "memory");
        else                 asm volatile("s_waitcnt vmcnt(0)" ::: "memory");
        __builtin_amdgcn_s_barrier();         // all waves' tile-t DMA landed
        __builtin_amdgcn_sched_barrier(0);    // pin ds_reads below (rule 18)

        const unsigned short* lA = lsm + (iter & 3) * 8192;
        const unsigned short* lB = lA + 4096;

        v8s bfr[4];
#pragma unroll
        for (int ns = 0; ns < 4; ++ns) {
            int row = wn * 64 + ns * 16 + low;
            bfr[ns] = *(const v8s*)(lB + (row * 4 + (quad ^ (row & 3))) * 8);
        }
#pragma unroll
        for (int ms = 0; ms < 4; ++ms) {
            int row = wm * 64 + ms * 16 + low;
            v8s af = *(const v8s*)(lA + (row * 4 + (quad ^ (row & 3))) * 8);
#pragma unroll
            for (int ns = 0; ns < 4; ++ns)
                acc[ms][ns] = bmfma(af, bfr[ns], acc[ms][ns]);
        }
    }

    const int tt = tN >> 9;  // block-uniform region id
    if (tt != 2) {
#pragma unroll
        for (int ms = 0; ms < 4; ++ms) {
#pragma unroll
            for (int reg = 0; reg < 4; ++reg) {
                const int row = tM + wm * 64 + ms * 16 + quad * 4 + reg;
                const int b = row >> 11, i = row & 2047;
                float kacc = 0.f;
#pragma unroll
                for (int ns = 0; ns < 4; ++ns) {
                    const int col = tN + wn * 64 + ns * 16 + low;
                    float dot = acc[ms][ns][reg];
                    float val = sqrtf(fmaxf(Asq[row] + Bsq[col] - 2.f * dot, 0.f)) - 32.f;
                    int h = (col >> 6) & 7, d = col & 63, bh = b * 8 + h;
                    if (tt == 0) {
                        QKV[((size_t)bh * 2048 + i) * 64 + d] =
                            f2bf(val * 0.36067376022224085f);  // 2*scale*log2e
                    } else {
                        QKV[HSZ + ((size_t)bh * 2048 + i) * 64 + d] = f2bf(val);
                        kacc += val * val;
                    }
                }
                if (tt == 1) {
#pragma unroll
                    for (int d = 1; d < 16; d <<= 1) kacc += __shfl_xor(kacc, d);
                    if (low == 0) {
                        int h = ((tN + wn * 64) >> 6) & 7;
                        // negated: serves as flash_attn's softmax C-init directly
                        Ksqc[(size_t)(b * 8 + h) * 2048 + i] = -kacc * 0.18033688011112042f;
                    }
                }
            }
        }
    } else {
        // v blocks: compute all vals, then 2-pass LDS transpose for coalesced
        // [bh][d][i] stores. lT: [col 0..127][row 0..63], stride 72 shorts.
        u32 packed[4][4][2];
#pragma unroll
        for (int ms = 0; ms < 4; ++ms)
#pragma unroll
            for (int ns = 0; ns < 4; ++ns) {
                const int col = tN + wn * 64 + ns * 16 + low;
                float bs_ = Bsq[col];
#pragma unroll
                for (int rp = 0; rp < 2; ++rp) {
                    u32 pk = 0;
#pragma unroll
                    for (int sub = 0; sub < 2; ++sub) {
                        int reg = rp * 2 + sub;
                        int row = tM + wm * 64 + ms * 16 + quad * 4 + reg;
                        float val = sqrtf(fmaxf(Asq[row] + bs_
                                                - 2.f * acc[ms][ns][reg], 0.f)) - 32.f;
                        pk |= (u32)f2bf(val) << (16 * sub);
                    }
                    packed[ms][ns][rp] = pk;
                }
            }
        u32* lT32 = (u32*)lsm;
#pragma unroll
        for (int p = 0; p < 2; ++p) {
            __syncthreads();
            if (wm == p) {
#pragma unroll
                for (int ms = 0; ms < 4; ++ms)
#pragma unroll
                    for (int ns = 0; ns < 4; ++ns) {
                        int cl = wn * 64 + ns * 16 + low;
#pragma unroll
                        for (int rp = 0; rp < 2; ++rp)
                            lT32[cl * 36 + ms * 8 + quad * 2 + rp] = packed[ms][ns][rp];
                    }
            }
            __syncthreads();
#pragma unroll
            for (int cc = 0; cc < 4; ++cc) {
                int col = cc * 32 + (t >> 3);
                int i0 = (t & 7) * 8;
                uint4 vvv = *(const uint4*)(lsm + col * 72 + i0);
                int colg = tN + col;
                int h = (colg >> 6) & 7, d = colg & 63;
                int rowg = tM + p * 64 + i0;
                int b = rowg >> 11, i = rowg & 2047;
                *(uint4*)(QKV + 2 * HSZ
                          + ((size_t)((b * 8 + h) * 64 + d)) * 2048 + i) = vvv;
            }
        }
    }
    (void)0;
}

// ---------------------------------------------------------------------------
// Flash attention v16 = v15 body (split=1, KVBLK=64, XCD swizzle, ILP pairs,
// raw v_exp_f32) with the cdist-v3 4-BUFFER DEPTH-2 schedule replacing the
// 2-barrier dbuf loop: iter t stages tile t+2 into buf (t+2)&3, waits
// vmcnt(8) (excludes the 2 in-flight prefetches; tile-t loads are 2 iters
// old), ONE barrier, compute. Halves barrier count (32 vs 64) and makes the
// current-buf wait structurally free.
// Race proof: buf (t+2)%4's last reader is compute(t-2), finished before
// barrier(t-1), which precedes STAGE(t+2) in program order (verified on
// gemm_cdist v3, round 13).
// LDS 72 KB -> 2 blocks/CU (= grid 512 / 256 CUs; residency unchanged).
__launch_bounds__(256, 2)
__global__ void flash_attn(const unsigned short* __restrict__ Q,
                           const unsigned short* __restrict__ K,
                           const unsigned short* __restrict__ VT,
                           const float* __restrict__ Ksqc,
                           unsigned short* __restrict__ OP,
                           float* __restrict__ Osqp)
{
    __shared__ unsigned short lK[4][64 * 64];   // [j][d], XOR-8 swizzle
    __shared__ unsigned short lV[4][64 * 64];   // [d][j], XOR-8 swizzle
    __shared__ float lKqA[2048];                // whole-bh -ksq*c, staged once
    const int t = threadIdx.x, lane = t & 63, w = t >> 6;
    const int i31 = lane & 31, h = lane >> 5;
    // XCD-aware decode of the 1D grid (T1)
    const int bid = blockIdx.x;
    const int bh = (bid & 7) * 4 + (bid >> 7);      // [0,32)
    const int qt = (bid >> 3) & 15;                 // [0,16)
    const size_t base = (size_t)bh * (2048 * 64);
    const int row0 = qt * 128 + w * 32;

    // Q fragments (B-operand layout): qfr[kt] = Q[row0+i31][16kt+8h..+7]
    v8s qfr[4];
#pragma unroll
    for (int kt = 0; kt < 4; ++kt)
        qfr[kt] = *(const v8s*)(Q + base + (size_t)(row0 + i31) * 64 + kt * 16 + h * 8);

    v16f o[2];
    float lacc = 0.f;
#pragma unroll
    for (int dt = 0; dt < 2; ++dt)
#pragma unroll
        for (int r = 0; r < 16; ++r) o[dt][r] = 0.f;

    const unsigned short* kg = K + base;
    const unsigned short* vg = VT + (size_t)bh * 64 * 2048;
    const float* kqg = Ksqc + (size_t)bh * 2048;

    auto STAGE = [&](int buf) {   // exactly 4 async16 per thread (uniform)
#pragma unroll
        for (int is = 0; is < 2; ++is) {
            int slot = is * 256 + t;
            int r = slot >> 3, bp = slot & 7, bs = bp ^ (r & 7);
            async16(kg + (size_t)r * 64 + bs * 8, &lK[buf][slot * 8]);
        }
#pragma unroll
        for (int is = 0; is < 2; ++is) {
            int slot = is * 256 + t;
            int r = slot >> 3, bp = slot & 7, bs = bp ^ (r & 7);
            async16(vg + (size_t)r * 2048 + bs * 8, &lV[buf][slot * 8]);
        }
        kg += 64 * 64; vg += 64;
    };

    // full per-tile body: QK(T0)+QK(T1) MFMAs back-to-back, then exp/pack+PV
    // per T (ILP pairing from v13). cb = LDS buffer, kqoff = lKqA offset.
    auto COMPUTE = [&](int cb, int kqoff) {
        const int jrow0 = i31, jrow1 = 32 + i31;
        v8s kf0[4], kf1[4];
#pragma unroll
        for (int kt = 0; kt < 4; ++kt) {
            kf0[kt] = *(const v8s*)(&lK[cb][(jrow0 * 8 + ((2 * kt + h) ^ (jrow0 & 7))) * 8]);
            kf1[kt] = *(const v8s*)(&lK[cb][(jrow1 * 8 + ((2 * kt + h) ^ (jrow1 & 7))) * 8]);
        }
        v16f sa0, sa1;
#pragma unroll
        for (int r1 = 0; r1 < 4; ++r1) {
            v4f kq0 = *(const v4f*)(&lKqA[kqoff + r1 * 8 + h * 4]);
            v4f kq1 = *(const v4f*)(&lKqA[kqoff + 32 + r1 * 8 + h * 4]);
#pragma unroll
            for (int u = 0; u < 4; ++u) {
                sa0[4 * r1 + u] = kq0[u];
                sa1[4 * r1 + u] = kq1[u];
            }
        }
#pragma unroll
        for (int kt = 0; kt < 4; ++kt) sa0 = bmfma32(kf0[kt], qfr[kt], sa0);
#pragma unroll
        for (int kt = 0; kt < 4; ++kt) sa1 = bmfma32(kf1[kt], qfr[kt], sa1);

        u32 pk0[8];
#pragma unroll
        for (int r1 = 0; r1 < 4; ++r1) {
            float p0 = fexp2(sa0[4 * r1 + 0]);
            float p1 = fexp2(sa0[4 * r1 + 1]);
            float p2 = fexp2(sa0[4 * r1 + 2]);
            float p3 = fexp2(sa0[4 * r1 + 3]);
            lacc += (p0 + p1) + (p2 + p3);
            pk0[2 * r1] = __builtin_amdgcn_perm(
                __builtin_bit_cast(u32, p1), __builtin_bit_cast(u32, p0),
                0x07060302u);
            pk0[2 * r1 + 1] = __builtin_amdgcn_perm(
                __builtin_bit_cast(u32, p3), __builtin_bit_cast(u32, p2),
                0x07060302u);
        }
#pragma unroll
        for (int c2 = 0; c2 < 2; ++c2) {
            const int jb = 2 * c2;               // T=0: jb = 0, 2
            v8s vf[2];
#pragma unroll
            for (int dt = 0; dt < 2; ++dt) {
                const int drow = dt * 32 + i31;
                vf[dt] = *(const v8s*)(&lV[cb][(drow * 8 + ((jb + h) ^ (drow & 7))) * 8]);
            }
            uint4 dd;
            swap32(pk0[4 * c2 + 0], pk0[4 * c2 + 2], dd.x, dd.z);
            swap32(pk0[4 * c2 + 1], pk0[4 * c2 + 3], dd.y, dd.w);
            v8s af = __builtin_bit_cast(v8s, dd);
            o[0] = bmfma32(af, vf[0], o[0]);
            o[1] = bmfma32(af, vf[1], o[1]);
        }

        u32 pk1[8];
#pragma unroll
        for (int r1 = 0; r1 < 4; ++r1) {
            float p0 = fexp2(sa1[4 * r1 + 0]);
            float p1 = fexp2(sa1[4 * r1 + 1]);
            float p2 = fexp2(sa1[4 * r1 + 2]);
            float p3 = fexp2(sa1[4 * r1 + 3]);
            lacc += (p0 + p1) + (p2 + p3);
            pk1[2 * r1] = __builtin_amdgcn_perm(
                __builtin_bit_cast(u32, p1), __builtin_bit_cast(u32, p0),
                0x07060302u);
            pk1[2 * r1 + 1] = __builtin_amdgcn_perm(
                __builtin_bit_cast(u32, p3), __builtin_bit_cast(u32, p2),
                0x07060302u);
        }
#pragma unroll
        for (int c2 = 0; c2 < 2; ++c2) {
            const int jb = 4 + 2 * c2;           // T=1: jb = 4, 6
            v8s vf[2];
#pragma unroll
            for (int dt = 0; dt < 2; ++dt) {
                const int drow = dt * 32 + i31;
                vf[dt] = *(const v8s*)(&lV[cb][(drow * 8 + ((jb + h) ^ (drow & 7))) * 8]);
            }
            uint4 dd;
            swap32(pk1[4 * c2 + 0], pk1[4 * c2 + 2], dd.x, dd.z);
            swap32(pk1[4 * c2 + 1], pk1[4 * c2 + 3], dd.y, dd.w);
            v8s af = __builtin_bit_cast(v8s, dd);
            o[0] = bmfma32(af, vf[0], o[0]);
            o[1] = bmfma32(af, vf[1], o[1]);
        }
    };

    // prologue: whole-bh Ksqc (8 KB, OLDEST in vmcnt queue) + tiles 0,1.
#pragma unroll
    for (int is = 0; is < 2; ++is) {
        int slot = is * 256 + t;
        async16(kqg + slot * 4, lKqA + slot * 4);
    }
    STAGE(0);
    STAGE(1);   // no drain: iter-0's vmcnt(8) covers kq + tile 0

    // main loop: iters 0..27 in groups of 4 (static buffer indices)
#pragma unroll 1
    for (int g = 0; g < 7; ++g) {
#pragma unroll
        for (int u = 0; u < 4; ++u) {
            STAGE((u + 2) & 3);                  // tile g*4+u+2 -> buf (t+2)&3
            asm volatile("s_waitcnt vmcnt(8)" ::: "memory");
            __builtin_amdgcn_s_barrier();
            __builtin_amdgcn_sched_barrier(0);
            COMPUTE(u, (g * 4 + u) * 64);
        }
    }
    // tail: iters 28..31
    STAGE(2);                                    // tile 30
    asm volatile("s_waitcnt vmcnt(8)" ::: "memory");
    __builtin_amdgcn_s_barrier();
    __builtin_amdgcn_sched_barrier(0);
    COMPUTE(0, 28 * 64);
    STAGE(3);                                    // tile 31
    asm volatile("s_waitcnt vmcnt(8)" ::: "memory");
    __builtin_amdgcn_s_barrier();
    __builtin_amdgcn_sched_barrier(0);
    COMPUTE(1, 29 * 64);
    asm volatile("s_waitcnt vmcnt(4)" ::: "memory");
    __builtin_amdgcn_s_barrier();
    __builtin_amdgcn_sched_barrier(0);
    COMPUTE(2, 30 * 64);
    asm volatile("s_waitcnt vmcnt(0)" ::: "memory");
    __builtin_amdgcn_s_barrier();
    __builtin_amdgcn_sched_barrier(0);
    COMPUTE(3, 31 * 64);

    // epilogue: normalize (l broadcast via shfl: C-layout row index is a lane
    // id), write final bf16 outp, emit per-head row-sq partials.
    const int b = bh >> 3, hh = bh & 7;
    lacc += __shfl_xor(lacc, 32);   // lanes now hold l for q-row row0+i31
    unsigned short* ob = OP + ((size_t)(b * 2048 + row0)) * 512 + hh * 64;
    float* osq = Osqp + (size_t)hh * 8192 + b * 2048 + row0;
#pragma unroll
    for (int r = 0; r < 16; ++r) {
        const int rl = (r & 3) + 8 * (r >> 2) + 4 * h;   // 0..31, row row0+rl
        float inv = 1.f / __shfl(lacc, rl);
        unsigned short e0 = f2bf(o[0][r] * inv);
        unsigned short e1 = f2bf(o[1][r] * inv);
        ob[(size_t)rl * 512 + i31] = e0;
        ob[(size_t)rl * 512 + 32 + i31] = e1;
        float f0 = bf2f(e0) + 32.f, f1 = bf2f(e1) + 32.f;
        float s = f0 * f0 + f1 * f1;
        s += __shfl_xor(s, 1);  s += __shfl_xor(s, 2);  s += __shfl_xor(s, 4);
        s += __shfl_xor(s, 8);  s += __shfl_xor(s, 16);
        if (i31 == 0) osq[rl] = s;
    }
}

// ---------------------------------------------------------------------------
// Output cdist GEMM v2: 128x64 tiles -> grid (64,8)=512 blocks.
// Double-buffered LDS (48 KB), ONE barrier per K-step.
// Asq = sum_h Osqp[h][row] (8 partials), staged once into LDS.
// val = sqrt(max(Asq+Bsq-2(dot+32*Brs),0)) -> fp32 OUT [8192][512].
__launch_bounds__(256, 2)
__global__ void gemm_out(const unsigned short* __restrict__ A,
                         const unsigned short* __restrict__ B,
                         const float* __restrict__ Osqp,
                         const float* __restrict__ Bsq,
                         const float* __restrict__ Brs,
                         float* __restrict__ OUT)
{
    __shared__ unsigned short lA[2][128 * 64];
    __shared__ unsigned short lB[2][64 * 64];
    __shared__ float lAsq[128];
    const int t = threadIdx.x;
    const int lane = t & 63, w = t >> 6;
    const int low = lane & 15, quad = lane >> 4;
    const int wm = w & 1, wn = w >> 1;
    const int tM = blockIdx.x * 128, tN = blockIdx.y * 64;

    if (t < 128) {
        float s = 0.f;
#pragma unroll
        for (int hh = 0; hh < 8; ++hh) s += Osqp[(size_t)hh * 8192 + tM + t];
        lAsq[t] = s;
    }

    v4f acc[4][2];
#pragma unroll
    for (int a = 0; a < 4; ++a)
#pragma unroll
        for (int b = 0; b < 2; ++b) acc[a][b] = (v4f){0.f, 0.f, 0.f, 0.f};

    int kstage = 0;
    auto STAGE = [&](int buf) {
#pragma unroll
        for (int is = 0; is < 4; ++is) {
            int slot = is * 256 + t;
            int r = slot >> 3, bp = slot & 7, bs = bp ^ (r & 7);
            async16(A + (size_t)(tM + r) * 512 + kstage + bs * 8, &lA[buf][slot * 8]);
        }
#pragma unroll
        for (int is = 0; is < 2; ++is) {
            int slot = is * 256 + t;
            int r = slot >> 3, bp = slot & 7, bs = bp ^ (r & 7);
            async16(B + (size_t)(tN + r) * 512 + kstage + bs * 8, &lB[buf][slot * 8]);
        }
        kstage += 64;
    };

    STAGE(0);
    __syncthreads();   // prologue drain: k-tile 0 resident (also covers lAsq)

#pragma unroll 2
    for (int iter = 0; iter < 8; ++iter) {
        const int c = iter & 1;
        if (iter < 7) STAGE(1 - c);   // overlaps compute below

        v8s bfr[2][2];
#pragma unroll
        for (int ns = 0; ns < 2; ++ns) {
            int row = wn * 32 + ns * 16 + low;
#pragma unroll
            for (int kc = 0; kc < 2; ++kc)
                bfr[ns][kc] = *(const v8s*)(&lB[c][(row * 8 + ((kc * 4 + quad) ^ (row & 7))) * 8]);
        }
#pragma unroll
        for (int ms = 0; ms < 4; ++ms) {
            int row = wm * 64 + ms * 16 + low;
            v8s af0 = *(const v8s*)(&lA[c][(row * 8 + ((0 + quad) ^ (row & 7))) * 8]);
            v8s af1 = *(const v8s*)(&lA[c][(row * 8 + ((4 + quad) ^ (row & 7))) * 8]);
#pragma unroll
            for (int ns = 0; ns < 2; ++ns) {
                acc[ms][ns] = bmfma(af0, bfr[ns][0], acc[ms][ns]);
                acc[ms][ns] = bmfma(af1, bfr[ns][1], acc[ms][ns]);
            }
        }
        __syncthreads();   // implicit drain; next buf ready before next STAGE
    }

#pragma unroll
    for (int ms = 0; ms < 4; ++ms) {
#pragma unroll
        for (int ns = 0; ns < 2; ++ns) {
#pragma unroll
            for (int reg = 0; reg < 4; ++reg) {
                int rloc = wm * 64 + ms * 16 + quad * 4 + reg;
                int row = tM + rloc;
                int col = tN + wn * 32 + ns * 16 + low;
                float val = sqrtf(fmaxf(lAsq[rloc] + Bsq[col]
                                        - 2.f * (acc[ms][ns][reg] + 32.f * Brs[col]), 0.f));
                OUT[(size_t)row * 512 + col] = val;
            }
        }
    }
}

// ---------------------------------------------------------------------------
extern "C" void kernel_launch(void* const* d_in, const int* in_sizes, int n_in,
                              void* d_out, int out_size, void* d_ws, size_t ws_size,
                              hipStream_t stream)
{
    const float* x    = (const float*)d_in[0];   // [4,2048,512]
    const float* wqkv = (const float*)d_in[1];   // [1536,512]
    const float* wout = (const float*)d_in[2];   // [512,512]
    float* out = (float*)d_out;                  // [4,2048,512] fp32

    char* ws = (char*)d_ws;
    size_t off = 0;
    auto alloc = [&](size_t bytes) -> void* {
        void* p = ws + off;
        off += (bytes + 255) & ~(size_t)255;
        return p;
    };
    unsigned short* xb   = (unsigned short*)alloc(8192ull * 512 * 2);
    unsigned short* wqb  = (unsigned short*)alloc(1536ull * 512 * 2);
    unsigned short* wob  = (unsigned short*)alloc(512ull * 512 * 2);
    unsigned short* qkv  = (unsigned short*)alloc(3ull * HSZ * 2);      // q'', k', v'^T
    unsigned short* outp = (unsigned short*)alloc(8192ull * 512 * 2);
    float* xsq  = (float*)alloc(8192 * 4);
    float* wqsq = (float*)alloc(1536 * 4);
    float* wosq = (float*)alloc(512 * 4);
    float* wors = (float*)alloc(512 * 4);
    float* ksqc = (float*)alloc(65536ull * 4);
    float* osqp = (float*)alloc(8ull * 8192 * 4);   // per-h row-sq partials

    prep_all<<<2560, 256, 0, stream>>>(x, wqkv, wout, xb, wqb, wob,
                                       xsq, wqsq, wosq, wors);

    gemm_cdist<<<dim3(64, 12), 256, 0, stream>>>(xb, wqb, xsq, wqsq, qkv, ksqc);
    flash_attn<<<512, 256, 0, stream>>>(qkv, qkv + HSZ, qkv + 2 * HSZ,
                                        ksqc, outp, osqp);
    gemm_out<<<dim3(64, 8), 256, 0, stream>>>(outp, wob, osqp, wosq, wors, out);
}

// Round 15
// 156.026 us; speedup vs baseline: 1.0265x; 1.0265x over previous
//
#include <hip/hip_runtime.h>
#include <stdint.h>

typedef float v4f  __attribute__((ext_vector_type(4)));
typedef float v16f __attribute__((ext_vector_type(16)));
typedef short v8s  __attribute__((ext_vector_type(8)));
typedef uint32_t u32;

#define DEVI static __device__ __forceinline__

// fp32 -> bf16 (RNE), raw bits
DEVI unsigned short f2bf(float f) {
    u32 u = __builtin_bit_cast(u32, f);
    u = (u + 0x7fffu + ((u >> 16) & 1u)) >> 16;
    return (unsigned short)u;
}
DEVI float bf2f(unsigned short h) {
    u32 u = ((u32)h) << 16;
    return __builtin_bit_cast(float, u);
}

// raw v_exp_f32: OCML exp2f without -ffast-math wraps the instruction in a
// ~5-op guarded range-fixup; our exponents are in-range. (round-12: -15us)
DEVI float fexp2(float x) {
#if __has_builtin(__builtin_amdgcn_exp2f)
    return __builtin_amdgcn_exp2f(x);
#else
    float r;
    asm("v_exp_f32 %0, %1" : "=v"(r) : "v"(x));
    return r;
#endif
}

// async global->LDS, 16B per lane. HW dest = wave-uniform base + lane*16.
template <typename T>
DEVI void async16(const T* g, T* l) {
    __builtin_amdgcn_global_load_lds(
        (const __attribute__((address_space(1))) u32*)g,
        (__attribute__((address_space(3))) u32*)l, 16, 0, 0);
}

DEVI v4f bmfma(v8s a, v8s b, v4f c) {
    return __builtin_amdgcn_mfma_f32_16x16x32_bf16(a, b, c, 0, 0, 0);
}
DEVI v16f bmfma32(v8s a, v8s b, v16f c) {
    return __builtin_amdgcn_mfma_f32_32x32x16_bf16(a, b, c, 0, 0, 0);
}

#if __has_builtin(__builtin_amdgcn_permlane32_swap)
#define HAVE_PLSWAP 1
typedef unsigned int v2u __attribute__((ext_vector_type(2)));
#endif

// lo = [a.lanes0-31 | b.lanes0-31], hi = [a.lanes32-63 | b.lanes32-63]
DEVI void swap32(u32 a, u32 b, u32& lo, u32& hi) {
#ifdef HAVE_PLSWAP
    v2u r = __builtin_amdgcn_permlane32_swap(a, b, false, false);
    lo = r.x; hi = r.y;
#else
    u32 ax = __shfl_xor(a, 32), bx = __shfl_xor(b, 32);
    int hh = (threadIdx.x & 63) >> 5;
    lo = hh ? bx : a;
    hi = hh ? b : ax;
#endif
}

static const size_t HSZ = 32ull * 2048 * 64;  // per q/k/v region, elements

// ---------------------------------------------------------------------------
// prep_all: one launch for the 3 input-prep passes.
// fp32 [R][512] -> bf16, row sum-of-squares, optional row sum.
__launch_bounds__(256, 2)
__global__ void prep_all(const float* __restrict__ X, const float* __restrict__ WQ,
                         const float* __restrict__ WO,
                         unsigned short* __restrict__ Xb, unsigned short* __restrict__ WQb,
                         unsigned short* __restrict__ WOb,
                         float* __restrict__ xsq, float* __restrict__ wqsq,
                         float* __restrict__ wosq, float* __restrict__ wors)
{
    const int bid = blockIdx.x;
    const int w = threadIdx.x >> 6, lane = threadIdx.x & 63;
    const float* src; unsigned short* dst; float* Sq; float* Rs = nullptr;
    int r;
    if (bid < 2048)      { src = X;  dst = Xb;  Sq = xsq;  r = bid * 4 + w; }
    else if (bid < 2432) { src = WQ; dst = WQb; Sq = wqsq; r = (bid - 2048) * 4 + w; }
    else                 { src = WO; dst = WOb; Sq = wosq; Rs = wors; r = (bid - 2432) * 4 + w; }

    const float* xr = src + (size_t)r * 512 + lane * 8;
    float4 a = *(const float4*)xr;
    float4 c = *(const float4*)(xr + 4);
    float s = a.x*a.x + a.y*a.y + a.z*a.z + a.w*a.w
            + c.x*c.x + c.y*c.y + c.z*c.z + c.w*c.w;
    float sm = a.x + a.y + a.z + a.w + c.x + c.y + c.z + c.w;
    uint4 pkv;
    unsigned short* e = (unsigned short*)&pkv;
    e[0] = f2bf(a.x); e[1] = f2bf(a.y); e[2] = f2bf(a.z); e[3] = f2bf(a.w);
    e[4] = f2bf(c.x); e[5] = f2bf(c.y); e[6] = f2bf(c.z); e[7] = f2bf(c.w);
    *(uint4*)(dst + (size_t)r * 512 + lane * 8) = pkv;
#pragma unroll
    for (int d = 32; d > 0; d >>= 1) {
        s  += __shfl_xor(s, d);
        sm += __shfl_xor(sm, d);
    }
    if (lane == 0) { Sq[r] = s; if (Rs) Rs[r] = sm; }
}

// ---------------------------------------------------------------------------
// QKV cdist GEMM v4: 128x128 tile, BK=32, 3-BUFFER depth-1 prefetch, ONE
// barrier per K-step, counted vmcnt. v3's 4-buffer/64KB silently cut
// residency 3->2 blocks/CU (grid 768 wants 3); 3 buffers = 48 KB restores it.
// Race proof: STAGE(t+1) overwrites buf (t+1)%3, last read by compute(t-2);
// every wave's compute(t-2) precedes barrier(t-1) in program order, which
// precedes STAGE(t+1). vmcnt(4) at iter t leaves only STAGE(t+1)'s 4 loads
// outstanding -> tile t (staged at iter t-1) is resident.
//   tt=0 (q): *2*scale*log2e -> q'' region [bh][i][d]
//   tt=1 (k): -> k' region [bh][j][d]; fused ksqc[bh][j] = -sum_d k'^2 * CK
//   tt=2 (v): -> v' region TRANSPOSED [bh][d][j], via LDS-transpose epilogue
__launch_bounds__(256, 2)
__global__ void gemm_cdist(const unsigned short* __restrict__ A,
                           const unsigned short* __restrict__ B,
                           const float* __restrict__ Asq,
                           const float* __restrict__ Bsq,
                           unsigned short* __restrict__ QKV,
                           float* __restrict__ Ksqc)
{
    // [buf 0..2][A 4096 | B 4096] shorts = 48 KB. Reused as lT in epilogue.
    __shared__ unsigned short lsm[3 * 8192];
    const int t = threadIdx.x;
    const int lane = t & 63, w = t >> 6;
    const int low = lane & 15, quad = lane >> 4;
    const int wm = w & 1, wn = w >> 1;
    const int tM = blockIdx.x * 128, tN = blockIdx.y * 128;

    v4f acc[4][4];
#pragma unroll
    for (int a = 0; a < 4; ++a)
#pragma unroll
        for (int b = 0; b < 4; ++b) acc[a][b] = (v4f){0.f, 0.f, 0.f, 0.f};

    int kstage = 0;
    auto STAGE = [&](int buf) {   // 4 async16 per thread (2 A + 2 B), uniform
        unsigned short* lA = lsm + buf * 8192;
        unsigned short* lB = lA + 4096;
#pragma unroll
        for (int is = 0; is < 2; ++is) {
            int slot = is * 256 + t;                 // 0..511
            int r = slot >> 2, bp = slot & 3, bs = bp ^ (r & 3);
            async16(A + (size_t)(tM + r) * 512 + kstage + bs * 8, lA + slot * 8);
            async16(B + (size_t)(tN + r) * 512 + kstage + bs * 8, lB + slot * 8);
        }
        kstage += 32;
    };

    STAGE(0);   // depth-1 prologue

#pragma unroll
    for (int iter = 0; iter < 16; ++iter) {
        if (iter < 15) {
            STAGE((iter + 1) % 3);
            asm volatile("s_waitcnt vmcnt(4)" ::: "memory");  // tile t resident
        } else {
            asm volatile("s_waitcnt vmcnt(0)" ::: "memory");
        }
        __builtin_amdgcn_s_barrier();         // all waves' tile-t DMA landed
        __builtin_amdgcn_sched_barrier(0);    // pin ds_reads below (rule 18)

        const unsigned short* lA = lsm + (iter % 3) * 8192;
        const unsigned short* lB = lA + 4096;

        v8s bfr[4];
#pragma unroll
        for (int ns = 0; ns < 4; ++ns) {
            int row = wn * 64 + ns * 16 + low;
            bfr[ns] = *(const v8s*)(lB + (row * 4 + (quad ^ (row & 3))) * 8);
        }
#pragma unroll
        for (int ms = 0; ms < 4; ++ms) {
            int row = wm * 64 + ms * 16 + low;
            v8s af = *(const v8s*)(lA + (row * 4 + (quad ^ (row & 3))) * 8);
#pragma unroll
            for (int ns = 0; ns < 4; ++ns)
                acc[ms][ns] = bmfma(af, bfr[ns], acc[ms][ns]);
        }
    }

    const int tt = tN >> 9;  // block-uniform region id
    if (tt != 2) {
#pragma unroll
        for (int ms = 0; ms < 4; ++ms) {
#pragma unroll
            for (int reg = 0; reg < 4; ++reg) {
                const int row = tM + wm * 64 + ms * 16 + quad * 4 + reg;
                const int b = row >> 11, i = row & 2047;
                float kacc = 0.f;
#pragma unroll
                for (int ns = 0; ns < 4; ++ns) {
                    const int col = tN + wn * 64 + ns * 16 + low;
                    float dot = acc[ms][ns][reg];
                    float val = sqrtf(fmaxf(Asq[row] + Bsq[col] - 2.f * dot, 0.f)) - 32.f;
                    int h = (col >> 6) & 7, d = col & 63, bh = b * 8 + h;
                    if (tt == 0) {
                        QKV[((size_t)bh * 2048 + i) * 64 + d] =
                            f2bf(val * 0.36067376022224085f);  // 2*scale*log2e
                    } else {
                        QKV[HSZ + ((size_t)bh * 2048 + i) * 64 + d] = f2bf(val);
                        kacc += val * val;
                    }
                }
                if (tt == 1) {
#pragma unroll
                    for (int d = 1; d < 16; d <<= 1) kacc += __shfl_xor(kacc, d);
                    if (low == 0) {
                        int h = ((tN + wn * 64) >> 6) & 7;
                        // negated: serves as flash_attn's softmax C-init directly
                        Ksqc[(size_t)(b * 8 + h) * 2048 + i] = -kacc * 0.18033688011112042f;
                    }
                }
            }
        }
    } else {
        // v blocks: compute all vals, then 2-pass LDS transpose for coalesced
        // [bh][d][i] stores. lT: [col 0..127][row 0..63], stride 72 shorts.
        u32 packed[4][4][2];
#pragma unroll
        for (int ms = 0; ms < 4; ++ms)
#pragma unroll
            for (int ns = 0; ns < 4; ++ns) {
                const int col = tN + wn * 64 + ns * 16 + low;
                float bs_ = Bsq[col];
#pragma unroll
                for (int rp = 0; rp < 2; ++rp) {
                    u32 pk = 0;
#pragma unroll
                    for (int sub = 0; sub < 2; ++sub) {
                        int reg = rp * 2 + sub;
                        int row = tM + wm * 64 + ms * 16 + quad * 4 + reg;
                        float val = sqrtf(fmaxf(Asq[row] + bs_
                                                - 2.f * acc[ms][ns][reg], 0.f)) - 32.f;
                        pk |= (u32)f2bf(val) << (16 * sub);
                    }
                    packed[ms][ns][rp] = pk;
                }
            }
        u32* lT32 = (u32*)lsm;
#pragma unroll
        for (int p = 0; p < 2; ++p) {
            __syncthreads();
            if (wm == p) {
#pragma unroll
                for (int ms = 0; ms < 4; ++ms)
#pragma unroll
                    for (int ns = 0; ns < 4; ++ns) {
                        int cl = wn * 64 + ns * 16 + low;
#pragma unroll
                        for (int rp = 0; rp < 2; ++rp)
                            lT32[cl * 36 + ms * 8 + quad * 2 + rp] = packed[ms][ns][rp];
                    }
            }
            __syncthreads();
#pragma unroll
            for (int cc = 0; cc < 4; ++cc) {
                int col = cc * 32 + (t >> 3);
                int i0 = (t & 7) * 8;
                uint4 vvv = *(const uint4*)(lsm + col * 72 + i0);
                int colg = tN + col;
                int h = (colg >> 6) & 7, d = colg & 63;
                int rowg = tM + p * 64 + i0;
                int b = rowg >> 11, i = rowg & 2047;
                *(uint4*)(QKV + 2 * HSZ
                          + ((size_t)((b * 8 + h) * 64 + d)) * 2048 + i) = vvv;
            }
        }
    }
    (void)0;
}

// ---------------------------------------------------------------------------
// Flash attention v16 (round-14, UNCHANGED): split=1, KVBLK=64, 4-buffer
// depth-2, counted vmcnt, XCD swizzle, ILP pairs, raw v_exp_f32.
__launch_bounds__(256, 2)
__global__ void flash_attn(const unsigned short* __restrict__ Q,
                           const unsigned short* __restrict__ K,
                           const unsigned short* __restrict__ VT,
                           const float* __restrict__ Ksqc,
                           unsigned short* __restrict__ OP,
                           float* __restrict__ Osqp)
{
    __shared__ unsigned short lK[4][64 * 64];   // [j][d], XOR-8 swizzle
    __shared__ unsigned short lV[4][64 * 64];   // [d][j], XOR-8 swizzle
    __shared__ float lKqA[2048];                // whole-bh -ksq*c, staged once
    const int t = threadIdx.x, lane = t & 63, w = t >> 6;
    const int i31 = lane & 31, h = lane >> 5;
    // XCD-aware decode of the 1D grid (T1)
    const int bid = blockIdx.x;
    const int bh = (bid & 7) * 4 + (bid >> 7);      // [0,32)
    const int qt = (bid >> 3) & 15;                 // [0,16)
    const size_t base = (size_t)bh * (2048 * 64);
    const int row0 = qt * 128 + w * 32;

    // Q fragments (B-operand layout): qfr[kt] = Q[row0+i31][16kt+8h..+7]
    v8s qfr[4];
#pragma unroll
    for (int kt = 0; kt < 4; ++kt)
        qfr[kt] = *(const v8s*)(Q + base + (size_t)(row0 + i31) * 64 + kt * 16 + h * 8);

    v16f o[2];
    float lacc = 0.f;
#pragma unroll
    for (int dt = 0; dt < 2; ++dt)
#pragma unroll
        for (int r = 0; r < 16; ++r) o[dt][r] = 0.f;

    const unsigned short* kg = K + base;
    const unsigned short* vg = VT + (size_t)bh * 64 * 2048;
    const float* kqg = Ksqc + (size_t)bh * 2048;

    auto STAGE = [&](int buf) {   // exactly 4 async16 per thread (uniform)
#pragma unroll
        for (int is = 0; is < 2; ++is) {
            int slot = is * 256 + t;
            int r = slot >> 3, bp = slot & 7, bs = bp ^ (r & 7);
            async16(kg + (size_t)r * 64 + bs * 8, &lK[buf][slot * 8]);
        }
#pragma unroll
        for (int is = 0; is < 2; ++is) {
            int slot = is * 256 + t;
            int r = slot >> 3, bp = slot & 7, bs = bp ^ (r & 7);
            async16(vg + (size_t)r * 2048 + bs * 8, &lV[buf][slot * 8]);
        }
        kg += 64 * 64; vg += 64;
    };

    // full per-tile body: QK(T0)+QK(T1) MFMAs back-to-back, then exp/pack+PV
    // per T (ILP pairing from v13). cb = LDS buffer, kqoff = lKqA offset.
    auto COMPUTE = [&](int cb, int kqoff) {
        const int jrow0 = i31, jrow1 = 32 + i31;
        v8s kf0[4], kf1[4];
#pragma unroll
        for (int kt = 0; kt < 4; ++kt) {
            kf0[kt] = *(const v8s*)(&lK[cb][(jrow0 * 8 + ((2 * kt + h) ^ (jrow0 & 7))) * 8]);
            kf1[kt] = *(const v8s*)(&lK[cb][(jrow1 * 8 + ((2 * kt + h) ^ (jrow1 & 7))) * 8]);
        }
        v16f sa0, sa1;
#pragma unroll
        for (int r1 = 0; r1 < 4; ++r1) {
            v4f kq0 = *(const v4f*)(&lKqA[kqoff + r1 * 8 + h * 4]);
            v4f kq1 = *(const v4f*)(&lKqA[kqoff + 32 + r1 * 8 + h * 4]);
#pragma unroll
            for (int u = 0; u < 4; ++u) {
                sa0[4 * r1 + u] = kq0[u];
                sa1[4 * r1 + u] = kq1[u];
            }
        }
#pragma unroll
        for (int kt = 0; kt < 4; ++kt) sa0 = bmfma32(kf0[kt], qfr[kt], sa0);
#pragma unroll
        for (int kt = 0; kt < 4; ++kt) sa1 = bmfma32(kf1[kt], qfr[kt], sa1);

        u32 pk0[8];
#pragma unroll
        for (int r1 = 0; r1 < 4; ++r1) {
            float p0 = fexp2(sa0[4 * r1 + 0]);
            float p1 = fexp2(sa0[4 * r1 + 1]);
            float p2 = fexp2(sa0[4 * r1 + 2]);
            float p3 = fexp2(sa0[4 * r1 + 3]);
            lacc += (p0 + p1) + (p2 + p3);
            pk0[2 * r1] = __builtin_amdgcn_perm(
                __builtin_bit_cast(u32, p1), __builtin_bit_cast(u32, p0),
                0x07060302u);
            pk0[2 * r1 + 1] = __builtin_amdgcn_perm(
                __builtin_bit_cast(u32, p3), __builtin_bit_cast(u32, p2),
                0x07060302u);
        }
#pragma unroll
        for (int c2 = 0; c2 < 2; ++c2) {
            const int jb = 2 * c2;               // T=0: jb = 0, 2
            v8s vf[2];
#pragma unroll
            for (int dt = 0; dt < 2; ++dt) {
                const int drow = dt * 32 + i31;
                vf[dt] = *(const v8s*)(&lV[cb][(drow * 8 + ((jb + h) ^ (drow & 7))) * 8]);
            }
            uint4 dd;
            swap32(pk0[4 * c2 + 0], pk0[4 * c2 + 2], dd.x, dd.z);
            swap32(pk0[4 * c2 + 1], pk0[4 * c2 + 3], dd.y, dd.w);
            v8s af = __builtin_bit_cast(v8s, dd);
            o[0] = bmfma32(af, vf[0], o[0]);
            o[1] = bmfma32(af, vf[1], o[1]);
        }

        u32 pk1[8];
#pragma unroll
        for (int r1 = 0; r1 < 4; ++r1) {
            float p0 = fexp2(sa1[4 * r1 + 0]);
            float p1 = fexp2(sa1[4 * r1 + 1]);
            float p2 = fexp2(sa1[4 * r1 + 2]);
            float p3 = fexp2(sa1[4 * r1 + 3]);
            lacc += (p0 + p1) + (p2 + p3);
            pk1[2 * r1] = __builtin_amdgcn_perm(
                __builtin_bit_cast(u32, p1), __builtin_bit_cast(u32, p0),
                0x07060302u);
            pk1[2 * r1 + 1] = __builtin_amdgcn_perm(
                __builtin_bit_cast(u32, p3), __builtin_bit_cast(u32, p2),
                0x07060302u);
        }
#pragma unroll
        for (int c2 = 0; c2 < 2; ++c2) {
            const int jb = 4 + 2 * c2;           // T=1: jb = 4, 6
            v8s vf[2];
#pragma unroll
            for (int dt = 0; dt < 2; ++dt) {
                const int drow = dt * 32 + i31;
                vf[dt] = *(const v8s*)(&lV[cb][(drow * 8 + ((jb + h) ^ (drow & 7))) * 8]);
            }
            uint4 dd;
            swap32(pk1[4 * c2 + 0], pk1[4 * c2 + 2], dd.x, dd.z);
            swap32(pk1[4 * c2 + 1], pk1[4 * c2 + 3], dd.y, dd.w);
            v8s af = __builtin_bit_cast(v8s, dd);
            o[0] = bmfma32(af, vf[0], o[0]);
            o[1] = bmfma32(af, vf[1], o[1]);
        }
    };

    // prologue: whole-bh Ksqc (8 KB, OLDEST in vmcnt queue) + tiles 0,1.
#pragma unroll
    for (int is = 0; is < 2; ++is) {
        int slot = is * 256 + t;
        async16(kqg + slot * 4, lKqA + slot * 4);
    }
    STAGE(0);
    STAGE(1);   // no drain: iter-0's vmcnt(8) covers kq + tile 0

    // main loop: iters 0..27 in groups of 4 (static buffer indices)
#pragma unroll 1
    for (int g = 0; g < 7; ++g) {
#pragma unroll
        for (int u = 0; u < 4; ++u) {
            STAGE((u + 2) & 3);                  // tile g*4+u+2 -> buf (t+2)&3
            asm volatile("s_waitcnt vmcnt(8)" ::: "memory");
            __builtin_amdgcn_s_barrier();
            __builtin_amdgcn_sched_barrier(0);
            COMPUTE(u, (g * 4 + u) * 64);
        }
    }
    // tail: iters 28..31
    STAGE(2);                                    // tile 30
    asm volatile("s_waitcnt vmcnt(8)" ::: "memory");
    __builtin_amdgcn_s_barrier();
    __builtin_amdgcn_sched_barrier(0);
    COMPUTE(0, 28 * 64);
    STAGE(3);                                    // tile 31
    asm volatile("s_waitcnt vmcnt(8)" ::: "memory");
    __builtin_amdgcn_s_barrier();
    __builtin_amdgcn_sched_barrier(0);
    COMPUTE(1, 29 * 64);
    asm volatile("s_waitcnt vmcnt(4)" ::: "memory");
    __builtin_amdgcn_s_barrier();
    __builtin_amdgcn_sched_barrier(0);
    COMPUTE(2, 30 * 64);
    asm volatile("s_waitcnt vmcnt(0)" ::: "memory");
    __builtin_amdgcn_s_barrier();
    __builtin_amdgcn_sched_barrier(0);
    COMPUTE(3, 31 * 64);

    // epilogue: normalize (l broadcast via shfl: C-layout row index is a lane
    // id), write final bf16 outp, emit per-head row-sq partials.
    const int b = bh >> 3, hh = bh & 7;
    lacc += __shfl_xor(lacc, 32);   // lanes now hold l for q-row row0+i31
    unsigned short* ob = OP + ((size_t)(b * 2048 + row0)) * 512 + hh * 64;
    float* osq = Osqp + (size_t)hh * 8192 + b * 2048 + row0;
#pragma unroll
    for (int r = 0; r < 16; ++r) {
        const int rl = (r & 3) + 8 * (r >> 2) + 4 * h;   // 0..31, row row0+rl
        float inv = 1.f / __shfl(lacc, rl);
        unsigned short e0 = f2bf(o[0][r] * inv);
        unsigned short e1 = f2bf(o[1][r] * inv);
        ob[(size_t)rl * 512 + i31] = e0;
        ob[(size_t)rl * 512 + 32 + i31] = e1;
        float f0 = bf2f(e0) + 32.f, f1 = bf2f(e1) + 32.f;
        float s = f0 * f0 + f1 * f1;
        s += __shfl_xor(s, 1);  s += __shfl_xor(s, 2);  s += __shfl_xor(s, 4);
        s += __shfl_xor(s, 8);  s += __shfl_xor(s, 16);
        if (i31 == 0) osq[rl] = s;
    }
}

// ---------------------------------------------------------------------------
// Output cdist GEMM v3: 128x64 tiles, BK=32, 3-BUFFER depth-1 prefetch, ONE
// barrier per K-step (same proven schedule as cdist v4; replaces the
// 2-barrier vmcnt(0)-drain loop). 3 x 12 KB = 36 KB LDS.
// Asq = sum_h Osqp[h][row] (8 partials), staged once into LDS.
// val = sqrt(max(Asq+Bsq-2(dot+32*Brs),0)) -> fp32 OUT [8192][512].
__launch_bounds__(256, 2)
__global__ void gemm_out(const unsigned short* __restrict__ A,
                         const unsigned short* __restrict__ B,
                         const float* __restrict__ Osqp,
                         const float* __restrict__ Bsq,
                         const float* __restrict__ Brs,
                         float* __restrict__ OUT)
{
    // [buf 0..2][A 4096 | B 2048] shorts = 36 KB
    __shared__ unsigned short lsm[3 * 6144];
    __shared__ float lAsq[128];
    const int t = threadIdx.x;
    const int lane = t & 63, w = t >> 6;
    const int low = lane & 15, quad = lane >> 4;
    const int wm = w & 1, wn = w >> 1;
    const int tM = blockIdx.x * 128, tN = blockIdx.y * 64;

    if (t < 128) {
        float s = 0.f;
#pragma unroll
        for (int hh = 0; hh < 8; ++hh) s += Osqp[(size_t)hh * 8192 + tM + t];
        lAsq[t] = s;
    }

    v4f acc[4][2];
#pragma unroll
    for (int a = 0; a < 4; ++a)
#pragma unroll
        for (int b = 0; b < 2; ++b) acc[a][b] = (v4f){0.f, 0.f, 0.f, 0.f};

    int kstage = 0;
    auto STAGE = [&](int buf) {   // 3 async16 per thread (2 A + 1 B), uniform
        unsigned short* lA = lsm + buf * 6144;
        unsigned short* lB = lA + 4096;
#pragma unroll
        for (int is = 0; is < 2; ++is) {
            int slot = is * 256 + t;                 // A: 512 slots
            int r = slot >> 2, bp = slot & 3, bs = bp ^ (r & 3);
            async16(A + (size_t)(tM + r) * 512 + kstage + bs * 8, lA + slot * 8);
        }
        {
            int slot = t;                            // B: 256 slots
            int r = slot >> 2, bp = slot & 3, bs = bp ^ (r & 3);
            async16(B + (size_t)(tN + r) * 512 + kstage + bs * 8, lB + slot * 8);
        }
        kstage += 32;
    };

    STAGE(0);   // depth-1 prologue

#pragma unroll
    for (int iter = 0; iter < 16; ++iter) {
        if (iter < 15) {
            STAGE((iter + 1) % 3);
            asm volatile("s_waitcnt vmcnt(3)" ::: "memory");  // tile t resident
        } else {
            asm volatile("s_waitcnt vmcnt(0)" ::: "memory");
        }
        __builtin_amdgcn_s_barrier();   // also makes lAsq visible (iter 0)
        __builtin_amdgcn_sched_barrier(0);

        const unsigned short* lA = lsm + (iter % 3) * 6144;
        const unsigned short* lB = lA + 4096;

        v8s bfr[2];
#pragma unroll
        for (int ns = 0; ns < 2; ++ns) {
            int row = wn * 32 + ns * 16 + low;
            bfr[ns] = *(const v8s*)(lB + (row * 4 + (quad ^ (row & 3))) * 8);
        }
#pragma unroll
        for (int ms = 0; ms < 4; ++ms) {
            int row = wm * 64 + ms * 16 + low;
            v8s af = *(const v8s*)(lA + (row * 4 + (quad ^ (row & 3))) * 8);
#pragma unroll
            for (int ns = 0; ns < 2; ++ns)
                acc[ms][ns] = bmfma(af, bfr[ns], acc[ms][ns]);
        }
    }

#pragma unroll
    for (int ms = 0; ms < 4; ++ms) {
#pragma unroll
        for (int ns = 0; ns < 2; ++ns) {
#pragma unroll
            for (int reg = 0; reg < 4; ++reg) {
                int rloc = wm * 64 + ms * 16 + quad * 4 + reg;
                int row = tM + rloc;
                int col = tN + wn * 32 + ns * 16 + low;
                float val = sqrtf(fmaxf(lAsq[rloc] + Bsq[col]
                                        - 2.f * (acc[ms][ns][reg] + 32.f * Brs[col]), 0.f));
                OUT[(size_t)row * 512 + col] = val;
            }
        }
    }
}

// ---------------------------------------------------------------------------
extern "C" void kernel_launch(void* const* d_in, const int* in_sizes, int n_in,
                              void* d_out, int out_size, void* d_ws, size_t ws_size,
                              hipStream_t stream)
{
    const float* x    = (const float*)d_in[0];   // [4,2048,512]
    const float* wqkv = (const float*)d_in[1];   // [1536,512]
    const float* wout = (const float*)d_in[2];   // [512,512]
    float* out = (float*)d_out;                  // [4,2048,512] fp32

    char* ws = (char*)d_ws;
    size_t off = 0;
    auto alloc = [&](size_t bytes) -> void* {
        void* p = ws + off;
        off += (bytes + 255) & ~(size_t)255;
        return p;
    };
    unsigned short* xb   = (unsigned short*)alloc(8192ull * 512 * 2);
    unsigned short* wqb  = (unsigned short*)alloc(1536ull * 512 * 2);
    unsigned short* wob  = (unsigned short*)alloc(512ull * 512 * 2);
    unsigned short* qkv  = (unsigned short*)alloc(3ull * HSZ * 2);      // q'', k', v'^T
    unsigned short* outp = (unsigned short*)alloc(8192ull * 512 * 2);
    float* xsq  = (float*)alloc(8192 * 4);
    float* wqsq = (float*)alloc(1536 * 4);
    float* wosq = (float*)alloc(512 * 4);
    float* wors = (float*)alloc(512 * 4);
    float* ksqc = (float*)alloc(65536ull * 4);
    float* osqp = (float*)alloc(8ull * 8192 * 4);   // per-h row-sq partials

    prep_all<<<2560, 256, 0, stream>>>(x, wqkv, wout, xb, wqb, wob,
                                       xsq, wqsq, wosq, wors);

    gemm_cdist<<<dim3(64, 12), 256, 0, stream>>>(xb, wqb, xsq, wqsq, qkv, ksqc);
    flash_attn<<<512, 256, 0, stream>>>(qkv, qkv + HSZ, qkv + 2 * HSZ,
                                        ksqc, outp, osqp);
    gemm_out<<<dim3(64, 8), 256, 0, stream>>>(outp, wob, osqp, wosq, wors, out);
}